// Round 2
// baseline (912.121 us; speedup 1.0000x reference)
//
#include <hip/hip_runtime.h>
#include <hip/hip_fp16.h>

// ---------------------------------------------------------------------------
// Qwen2 attention block, MI355X (gfx950).
// B=2 S=2048 H=3584 NH=28 NKV=4 D=128  QS=3584 KVS=512 QKV=4608  M=B*S=4096
// fp16 MFMA (16x16x32) everywhere; fp32 accumulate; fp32 softmax/rope.
// R1: attention restructured for GQA K/V sharing — 7 waves/block = 7 q-heads
//     of one kv-group share each K/V LDS staging; LPT (longest-first) order.
// ---------------------------------------------------------------------------

typedef _Float16 h8 __attribute__((ext_vector_type(8)));
typedef _Float16 h4 __attribute__((ext_vector_type(4)));
typedef float f4 __attribute__((ext_vector_type(4)));

__device__ __forceinline__ void gload_lds16(const void* g, void* l) {
  __builtin_amdgcn_global_load_lds(
      (const __attribute__((address_space(1))) void*)g,
      (__attribute__((address_space(3))) void*)l, 16, 0, 0);
}

// ---------------- elementwise cast fp32 -> fp16 ----------------
__global__ __launch_bounds__(256)
void cast_f32_to_f16(const float4* __restrict__ in, h4* __restrict__ out, int n4) {
  int i = blockIdx.x * 256 + threadIdx.x;
  if (i < n4) {
    float4 v = in[i];
    h4 o;
    o.x = (_Float16)v.x; o.y = (_Float16)v.y; o.z = (_Float16)v.z; o.w = (_Float16)v.w;
    out[i] = o;
  }
}

// ---------------- transpose + cast: W[K][N] fp32 -> Wt[N][K] fp16 ----------------
__global__ __launch_bounds__(256)
void transpose_cast(const float* __restrict__ W, _Float16* __restrict__ Wt, int K, int N) {
  __shared__ float tile[32][33];
  int n0 = blockIdx.x * 32, k0 = blockIdx.y * 32;
  int tx = threadIdx.x, ty = threadIdx.y;   // block (32,8)
#pragma unroll
  for (int i = ty; i < 32; i += 8)
    tile[i][tx] = W[(size_t)(k0 + i) * N + n0 + tx];
  __syncthreads();
#pragma unroll
  for (int i = ty; i < 32; i += 8)
    Wt[(size_t)(n0 + i) * K + k0 + tx] = (_Float16)tile[tx][i];
}

// ---------------- GEMM: C[M][N] = A[M][K] * Bt[N][K]^T (+bias) ----------------
// 128x128 block tile, BK=32, 256 threads (2x2 waves of 64x64), 16x16x32 fp16 MFMA.
template <bool OUT_H, bool BIAS>
__global__ __launch_bounds__(256, 2)
void gemm_kernel(const _Float16* __restrict__ A, const _Float16* __restrict__ Bt,
                 const float* __restrict__ bias, void* __restrict__ Cout,
                 int M, int N, int K) {
  __shared__ _Float16 As[128 * 32];
  __shared__ _Float16 Bs[128 * 32];
  const int tid = threadIdx.x;
  const int m0 = blockIdx.y * 128, n0 = blockIdx.x * 128;
  const int lane = tid & 63, wave = tid >> 6;
  const int wm = (wave >> 1) * 64, wn = (wave & 1) * 64;
  const int r_ld = tid >> 2;          // staging row (0..63)
  const int c_ld = (tid & 3) * 8;     // staging k-offset
  const int row_f = lane & 15, kg8 = (lane >> 4) * 8;

  f4 acc[4][4] = {};
  const _Float16* Ag = A + (size_t)m0 * K + c_ld;
  const _Float16* Bg = Bt + (size_t)n0 * K + c_ld;

  for (int kk = 0; kk < K; kk += 32) {
    __syncthreads();
    gload_lds16(Ag + (size_t)r_ld * K + kk,        As + tid * 8);
    gload_lds16(Ag + (size_t)(r_ld + 64) * K + kk, As + 64 * 32 + tid * 8);
    gload_lds16(Bg + (size_t)r_ld * K + kk,        Bs + tid * 8);
    gload_lds16(Bg + (size_t)(r_ld + 64) * K + kk, Bs + 64 * 32 + tid * 8);
    __syncthreads();
    h8 a_frag[4], b_frag[4];
#pragma unroll
    for (int t = 0; t < 4; ++t)
      a_frag[t] = *(const h8*)&As[(wm + t * 16 + row_f) * 32 + kg8];
#pragma unroll
    for (int t = 0; t < 4; ++t)
      b_frag[t] = *(const h8*)&Bs[(wn + t * 16 + row_f) * 32 + kg8];
#pragma unroll
    for (int i = 0; i < 4; ++i)
#pragma unroll
      for (int j = 0; j < 4; ++j)
        acc[i][j] = __builtin_amdgcn_mfma_f32_16x16x32_f16(a_frag[i], b_frag[j], acc[i][j], 0, 0, 0);
  }

  // epilogue: C/D layout col = lane&15, row = (lane>>4)*4 + r
  const int col_f = lane & 15, rgrp = (lane >> 4) * 4;
#pragma unroll
  for (int i = 0; i < 4; ++i) {
#pragma unroll
    for (int j = 0; j < 4; ++j) {
      const int col = n0 + wn + j * 16 + col_f;
      float bv = 0.0f;
      if (BIAS) bv = bias[col];
#pragma unroll
      for (int r = 0; r < 4; ++r) {
        const int row = m0 + wm + i * 16 + rgrp + r;
        const float v = acc[i][j][r] + bv;
        if (OUT_H) ((_Float16*)Cout)[(size_t)row * N + col] = (_Float16)v;
        else       ((float*)Cout)[(size_t)row * N + col] = v;
      }
    }
  }
}

// ---------------- RoPE + split + V transpose ----------------
__global__ __launch_bounds__(256)
void rope_kernel(const _Float16* __restrict__ qkv, const int* __restrict__ pos,
                 _Float16* __restrict__ q, _Float16* __restrict__ k,
                 _Float16* __restrict__ vt) {
  constexpr int S = 2048, NH = 28, NKV = 4, QKVW = 4608, QW = 3584, KVW = 512;
  const int token = blockIdx.x;
  const int b = token >> 11, s = token & 2047;
  const int p = pos[token];
  __shared__ float cs[64], sn[64];
  const int tid = threadIdx.x;
  if (tid < 64) {
    const float L = 0.31143075892695140f;  // log2(1e6)/64
    float inv = exp2f(-(float)tid * L);
    float ang = (float)p * inv;
    cs[tid] = cosf(ang);
    sn[tid] = sinf(ang);
  }
  __syncthreads();
  const _Float16* src = qkv + (size_t)token * QKVW;
  for (int i = tid; i < NH * 64; i += 256) {
    int hh = i >> 6, d = i & 63;
    float x1 = (float)src[hh * 128 + d];
    float x2 = (float)src[hh * 128 + d + 64];
    float c = cs[d], sv = sn[d];
    _Float16* dst = q + (size_t)token * QW + hh * 128 + d;
    dst[0]  = (_Float16)(x1 * c - x2 * sv);
    dst[64] = (_Float16)(x2 * c + x1 * sv);
  }
  for (int i = tid; i < NKV * 64; i += 256) {
    int hh = i >> 6, d = i & 63;
    float x1 = (float)src[QW + hh * 128 + d];
    float x2 = (float)src[QW + hh * 128 + d + 64];
    float c = cs[d], sv = sn[d];
    _Float16* dst = k + (size_t)token * KVW + hh * 128 + d;
    dst[0]  = (_Float16)(x1 * c - x2 * sv);
    dst[64] = (_Float16)(x2 * c + x1 * sv);
  }
  for (int i = tid; i < NKV * 128; i += 256) {
    int hh = i >> 7, d = i & 127;
    vt[(((size_t)b * NKV + hh) * 128 + d) * S + s] = src[QW + KVW + hh * 128 + d];
  }
}

// ---------------- flash attention (causal, GQA, KV shared across 7 heads) ----
// grid 1024 blocks x 448 threads. Block = (16 q-rows) x (7 heads of one kvh).
// wave w handles head kvh*7+w. K/V staged once per 64-key tile, shared.
// LPT: qt mapped descending so longest blocks dispatch first.
__global__ __launch_bounds__(448, 6)
void attn_kernel(const _Float16* __restrict__ Q,   // [B*S][NH*128] rope'd
                 const _Float16* __restrict__ Kh,  // [B*S][NKV*128] rope'd
                 const _Float16* __restrict__ Vt,  // [B][NKV][128][S]
                 _Float16* __restrict__ Oh) {      // [B*S][NH*128]
  constexpr int S = 2048, D = 128, NH = 28, NKV = 4;
  const int id = blockIdx.x;
  const int qt = 127 - (id >> 3);          // 16-row q tile, longest first
  const int b = (id >> 2) & 1, kvh = id & 3;
  const int tid = threadIdx.x, lane = tid & 63, wave = tid >> 6;  // wave 0..6
  const int h = kvh * 7 + wave;            // this wave's query head
  const int q0 = qt * 16;
  const int row_f = lane & 15, kg = lane >> 4, kg8 = (lane >> 4) * 8;

  __shared__ _Float16 Ks[4][64][32];   // [d_chunk][key][32 d] rows=64B
  __shared__ _Float16 Vs[2][128][32];  // [key_chunk][d][32 keys] rows=64B
  __shared__ _Float16 Ps[7][16][72];   // per-wave P^T scratch, padded stride

  // load Q fragments (A-operand layout) once
  h8 qf[4];
  {
    const _Float16* qrow = Q + ((size_t)(b * S + q0 + row_f) * NH + h) * D;
#pragma unroll
    for (int ks = 0; ks < 4; ++ks)
      qf[ks] = *(const h8*)(qrow + ks * 32 + kg8);
  }
  f4 o_acc[8] = {};
  float m_i[4] = {-1e30f, -1e30f, -1e30f, -1e30f};
  float l_i[4] = {0.f, 0.f, 0.f, 0.f};
  const float sc = 0.08838834764831845f * 1.4426950408889634f;  // scale * log2e

  const _Float16* kbase = Kh + ((size_t)(b * S) * NKV + kvh) * D;
  const _Float16* vbase = Vt + ((size_t)(b * NKV + kvh) * D) * S;

  const int kt_max = qt >> 2;  // last 64-key tile (diagonal)
  for (int kt = 0; kt <= kt_max; ++kt) {
    __syncthreads();
    if (tid < 256) {
      // stage K tile: 64 keys x 128 d, chunked by 32 d
#pragma unroll
      for (int is = 0; is < 4; ++is) {
        int off = (is * 256 + tid) * 8;
        int chunk = off >> 11;
        int key = (off >> 5) & 63;
        int dl = off & 31;
        gload_lds16(kbase + (size_t)(kt * 64 + key) * (NKV * D) + chunk * 32 + dl,
                    &Ks[0][0][0] + off);
      }
      // stage V tile: 128 d x 64 keys, chunked by 32 keys
#pragma unroll
      for (int is = 0; is < 4; ++is) {
        int off = (is * 256 + tid) * 8;
        int chunk = off >> 12;
        int d = (off >> 5) & 127;
        int kl = off & 31;
        gload_lds16(vbase + (size_t)d * S + kt * 64 + chunk * 32 + kl,
                    &Vs[0][0][0] + off);
      }
    }
    __syncthreads();

    // S = Q K^T  (16 q x 64 keys per wave)
    f4 s_acc[4] = {};
#pragma unroll
    for (int ks = 0; ks < 4; ++ks) {
#pragma unroll
      for (int nt = 0; nt < 4; ++nt) {
        h8 kf = *(const h8*)&Ks[ks][nt * 16 + row_f][kg8];
        s_acc[nt] = __builtin_amdgcn_mfma_f32_16x16x32_f16(qf[ks], kf, s_acc[nt], 0, 0, 0);
      }
    }

    // scaled scores (log2 domain) + causal mask on the diagonal tile
    float sv[4][4];
    const bool diag = (kt == kt_max);
#pragma unroll
    for (int nt = 0; nt < 4; ++nt) {
#pragma unroll
      for (int r = 0; r < 4; ++r) {
        float v = s_acc[nt][r] * sc;
        if (diag) {
          int key = kt * 64 + nt * 16 + row_f;
          int row = q0 + kg * 4 + r;
          if (key > row) v = -1e30f;
        }
        sv[nt][r] = v;
      }
    }
    // online softmax (rows live in 16-lane groups)
#pragma unroll
    for (int r = 0; r < 4; ++r) {
      float mx = fmaxf(fmaxf(sv[0][r], sv[1][r]), fmaxf(sv[2][r], sv[3][r]));
#pragma unroll
      for (int off = 8; off >= 1; off >>= 1)
        mx = fmaxf(mx, __shfl_xor(mx, off, 64));
      float mn = fmaxf(m_i[r], mx);
      float alpha = exp2f(m_i[r] - mn);
      m_i[r] = mn;
      float ssum = 0.f;
#pragma unroll
      for (int nt = 0; nt < 4; ++nt) {
        float p = exp2f(sv[nt][r] - mn);
        sv[nt][r] = p;
        ssum += p;
      }
#pragma unroll
      for (int off = 8; off >= 1; off >>= 1)
        ssum += __shfl_xor(ssum, off, 64);
      l_i[r] = l_i[r] * alpha + ssum;
#pragma unroll
      for (int dt = 0; dt < 8; ++dt) o_acc[dt][r] *= alpha;
    }
    // P (C-layout) -> Ps (A-layout source), per-wave scratch
#pragma unroll
    for (int nt = 0; nt < 4; ++nt)
#pragma unroll
      for (int r = 0; r < 4; ++r)
        Ps[wave][kg * 4 + r][nt * 16 + row_f] = (_Float16)sv[nt][r];

    // O += P V
#pragma unroll
    for (int kv = 0; kv < 2; ++kv) {
      h8 pf = *(const h8*)&Ps[wave][row_f][kv * 32 + kg8];
#pragma unroll
      for (int dt = 0; dt < 8; ++dt) {
        h8 vf = *(const h8*)&Vs[kv][dt * 16 + row_f][kg8];
        o_acc[dt] = __builtin_amdgcn_mfma_f32_16x16x32_f16(pf, vf, o_acc[dt], 0, 0, 0);
      }
    }
  }

  // epilogue: O /= l, store [token][h*128+d]
  float inv_l[4];
#pragma unroll
  for (int r = 0; r < 4; ++r) inv_l[r] = 1.0f / l_i[r];
#pragma unroll
  for (int dt = 0; dt < 8; ++dt) {
#pragma unroll
    for (int r = 0; r < 4; ++r) {
      const int tok = b * S + q0 + kg * 4 + r;
      const int d = dt * 16 + row_f;
      Oh[((size_t)tok * NH + h) * D + d] = (_Float16)(o_acc[dt][r] * inv_l[r]);
    }
  }
}

// ---------------------------------------------------------------------------
extern "C" void kernel_launch(void* const* d_in, const int* in_sizes, int n_in,
                              void* d_out, int out_size, void* d_ws, size_t ws_size,
                              hipStream_t stream) {
  const float* hidden    = (const float*)d_in[0];
  const int*   positions = (const int*)d_in[1];
  const float* Wqkv      = (const float*)d_in[2];
  const float* bqkv      = (const float*)d_in[3];
  const float* Wo        = (const float*)d_in[4];
  float* out = (float*)d_out;

  // workspace layout (bytes)
  char* ws = (char*)d_ws;
  _Float16* hs_h  = (_Float16*)(ws);              // 4096x3584 fp16 (later reused as attn out)
  _Float16* Wt    = (_Float16*)(ws + 29360128);   // max 4608x3584 fp16 (Wqkv^T then Wo^T)
  _Float16* qkv_h = (_Float16*)(ws + 62390272);   // 4096x4608 fp16
  _Float16* q_h   = (_Float16*)(ws + 100139008);  // 4096x3584 fp16
  _Float16* k_h   = (_Float16*)(ws + 129499136);  // 4096x512 fp16
  _Float16* vt_h  = (_Float16*)(ws + 133693440);  // 2x4x128x2048 fp16
  // total 137,887,744 bytes

  // 1. hidden fp32 -> fp16
  cast_f32_to_f16<<<14336, 256, 0, stream>>>((const float4*)hidden, (h4*)hs_h, 3670016);
  // 2. Wqkv^T fp16
  transpose_cast<<<dim3(4608 / 32, 3584 / 32), dim3(32, 8), 0, stream>>>(Wqkv, Wt, 3584, 4608);
  // 3. qkv = hidden @ Wqkv + b   (fp16 out)
  gemm_kernel<true, true><<<dim3(36, 32), 256, 0, stream>>>(hs_h, Wt, bqkv, qkv_h, 4096, 4608, 3584);
  // 4. rope + split + v-transpose
  rope_kernel<<<4096, 256, 0, stream>>>(qkv_h, positions, q_h, k_h, vt_h);
  // 5. Wo^T fp16 (reuse Wt; stream-ordered after GEMM1)
  transpose_cast<<<dim3(3584 / 32, 3584 / 32), dim3(32, 8), 0, stream>>>(Wo, Wt, 3584, 3584);
  // 6. flash attention -> attn fp16 (into hs_h, dead after GEMM1)
  attn_kernel<<<1024, 448, 0, stream>>>(q_h, k_h, vt_h, hs_h);
  // 7. out = attn @ Wo   (fp32 out)
  gemm_kernel<false, false><<<dim3(28, 32), 256, 0, stream>>>(hs_h, Wt, nullptr, out, 4096, 3584, 3584);
}

// Round 3
// 729.353 us; speedup vs baseline: 1.2506x; 1.2506x over previous
//
#include <hip/hip_runtime.h>
#include <hip/hip_fp16.h>

// ---------------------------------------------------------------------------
// Qwen2 attention block, MI355X (gfx950).
// B=2 S=2048 H=3584 NH=28 NKV=4 D=128  QS=3584 KVS=512 QKV=4608  M=B*S=4096
// fp16 MFMA (16x16x32) everywhere; fp32 accumulate; fp32 softmax/rope.
// R1: attention restructured for GQA K/V sharing — 7 waves/block = 7 q-heads.
// R2: __launch_bounds__(448,6) -> (448,2). The ,6 bound capped VGPRs at 40 ->
//     massive scratch spills (WRITE_SIZE 722 MB vs 29 MB legit). LDS (48KB,
//     3 blocks/CU = 21 waves/CU) is the intended occupancy limiter, not VGPR.
// ---------------------------------------------------------------------------

typedef _Float16 h8 __attribute__((ext_vector_type(8)));
typedef _Float16 h4 __attribute__((ext_vector_type(4)));
typedef float f4 __attribute__((ext_vector_type(4)));

__device__ __forceinline__ void gload_lds16(const void* g, void* l) {
  __builtin_amdgcn_global_load_lds(
      (const __attribute__((address_space(1))) void*)g,
      (__attribute__((address_space(3))) void*)l, 16, 0, 0);
}

// ---------------- elementwise cast fp32 -> fp16 ----------------
__global__ __launch_bounds__(256)
void cast_f32_to_f16(const float4* __restrict__ in, h4* __restrict__ out, int n4) {
  int i = blockIdx.x * 256 + threadIdx.x;
  if (i < n4) {
    float4 v = in[i];
    h4 o;
    o.x = (_Float16)v.x; o.y = (_Float16)v.y; o.z = (_Float16)v.z; o.w = (_Float16)v.w;
    out[i] = o;
  }
}

// ---------------- transpose + cast: W[K][N] fp32 -> Wt[N][K] fp16 ----------------
__global__ __launch_bounds__(256)
void transpose_cast(const float* __restrict__ W, _Float16* __restrict__ Wt, int K, int N) {
  __shared__ float tile[32][33];
  int n0 = blockIdx.x * 32, k0 = blockIdx.y * 32;
  int tx = threadIdx.x, ty = threadIdx.y;   // block (32,8)
#pragma unroll
  for (int i = ty; i < 32; i += 8)
    tile[i][tx] = W[(size_t)(k0 + i) * N + n0 + tx];
  __syncthreads();
#pragma unroll
  for (int i = ty; i < 32; i += 8)
    Wt[(size_t)(n0 + i) * K + k0 + tx] = (_Float16)tile[tx][i];
}

// ---------------- GEMM: C[M][N] = A[M][K] * Bt[N][K]^T (+bias) ----------------
// 128x128 block tile, BK=32, 256 threads (2x2 waves of 64x64), 16x16x32 fp16 MFMA.
template <bool OUT_H, bool BIAS>
__global__ __launch_bounds__(256, 2)
void gemm_kernel(const _Float16* __restrict__ A, const _Float16* __restrict__ Bt,
                 const float* __restrict__ bias, void* __restrict__ Cout,
                 int M, int N, int K) {
  __shared__ _Float16 As[128 * 32];
  __shared__ _Float16 Bs[128 * 32];
  const int tid = threadIdx.x;
  const int m0 = blockIdx.y * 128, n0 = blockIdx.x * 128;
  const int lane = tid & 63, wave = tid >> 6;
  const int wm = (wave >> 1) * 64, wn = (wave & 1) * 64;
  const int r_ld = tid >> 2;          // staging row (0..63)
  const int c_ld = (tid & 3) * 8;     // staging k-offset
  const int row_f = lane & 15, kg8 = (lane >> 4) * 8;

  f4 acc[4][4] = {};
  const _Float16* Ag = A + (size_t)m0 * K + c_ld;
  const _Float16* Bg = Bt + (size_t)n0 * K + c_ld;

  for (int kk = 0; kk < K; kk += 32) {
    __syncthreads();
    gload_lds16(Ag + (size_t)r_ld * K + kk,        As + tid * 8);
    gload_lds16(Ag + (size_t)(r_ld + 64) * K + kk, As + 64 * 32 + tid * 8);
    gload_lds16(Bg + (size_t)r_ld * K + kk,        Bs + tid * 8);
    gload_lds16(Bg + (size_t)(r_ld + 64) * K + kk, Bs + 64 * 32 + tid * 8);
    __syncthreads();
    h8 a_frag[4], b_frag[4];
#pragma unroll
    for (int t = 0; t < 4; ++t)
      a_frag[t] = *(const h8*)&As[(wm + t * 16 + row_f) * 32 + kg8];
#pragma unroll
    for (int t = 0; t < 4; ++t)
      b_frag[t] = *(const h8*)&Bs[(wn + t * 16 + row_f) * 32 + kg8];
#pragma unroll
    for (int i = 0; i < 4; ++i)
#pragma unroll
      for (int j = 0; j < 4; ++j)
        acc[i][j] = __builtin_amdgcn_mfma_f32_16x16x32_f16(a_frag[i], b_frag[j], acc[i][j], 0, 0, 0);
  }

  // epilogue: C/D layout col = lane&15, row = (lane>>4)*4 + r
  const int col_f = lane & 15, rgrp = (lane >> 4) * 4;
#pragma unroll
  for (int i = 0; i < 4; ++i) {
#pragma unroll
    for (int j = 0; j < 4; ++j) {
      const int col = n0 + wn + j * 16 + col_f;
      float bv = 0.0f;
      if (BIAS) bv = bias[col];
#pragma unroll
      for (int r = 0; r < 4; ++r) {
        const int row = m0 + wm + i * 16 + rgrp + r;
        const float v = acc[i][j][r] + bv;
        if (OUT_H) ((_Float16*)Cout)[(size_t)row * N + col] = (_Float16)v;
        else       ((float*)Cout)[(size_t)row * N + col] = v;
      }
    }
  }
}

// ---------------- RoPE + split + V transpose ----------------
__global__ __launch_bounds__(256)
void rope_kernel(const _Float16* __restrict__ qkv, const int* __restrict__ pos,
                 _Float16* __restrict__ q, _Float16* __restrict__ k,
                 _Float16* __restrict__ vt) {
  constexpr int S = 2048, NH = 28, NKV = 4, QKVW = 4608, QW = 3584, KVW = 512;
  const int token = blockIdx.x;
  const int b = token >> 11, s = token & 2047;
  const int p = pos[token];
  __shared__ float cs[64], sn[64];
  const int tid = threadIdx.x;
  if (tid < 64) {
    const float L = 0.31143075892695140f;  // log2(1e6)/64
    float inv = exp2f(-(float)tid * L);
    float ang = (float)p * inv;
    cs[tid] = cosf(ang);
    sn[tid] = sinf(ang);
  }
  __syncthreads();
  const _Float16* src = qkv + (size_t)token * QKVW;
  for (int i = tid; i < NH * 64; i += 256) {
    int hh = i >> 6, d = i & 63;
    float x1 = (float)src[hh * 128 + d];
    float x2 = (float)src[hh * 128 + d + 64];
    float c = cs[d], sv = sn[d];
    _Float16* dst = q + (size_t)token * QW + hh * 128 + d;
    dst[0]  = (_Float16)(x1 * c - x2 * sv);
    dst[64] = (_Float16)(x2 * c + x1 * sv);
  }
  for (int i = tid; i < NKV * 64; i += 256) {
    int hh = i >> 6, d = i & 63;
    float x1 = (float)src[QW + hh * 128 + d];
    float x2 = (float)src[QW + hh * 128 + d + 64];
    float c = cs[d], sv = sn[d];
    _Float16* dst = k + (size_t)token * KVW + hh * 128 + d;
    dst[0]  = (_Float16)(x1 * c - x2 * sv);
    dst[64] = (_Float16)(x2 * c + x1 * sv);
  }
  for (int i = tid; i < NKV * 128; i += 256) {
    int hh = i >> 7, d = i & 127;
    vt[(((size_t)b * NKV + hh) * 128 + d) * S + s] = src[QW + KVW + hh * 128 + d];
  }
}

// ---------------- flash attention (causal, GQA, KV shared across 7 heads) ----
// grid 1024 blocks x 448 threads. Block = (16 q-rows) x (7 heads of one kvh).
// wave w handles head kvh*7+w. K/V staged once per 64-key tile, shared.
// LPT: qt mapped descending so longest blocks dispatch first.
// launch_bounds (448,2): VGPR cap 256 — DO NOT tighten; (448,6) caused spills.
__global__ __launch_bounds__(448, 2)
void attn_kernel(const _Float16* __restrict__ Q,   // [B*S][NH*128] rope'd
                 const _Float16* __restrict__ Kh,  // [B*S][NKV*128] rope'd
                 const _Float16* __restrict__ Vt,  // [B][NKV][128][S]
                 _Float16* __restrict__ Oh) {      // [B*S][NH*128]
  constexpr int S = 2048, D = 128, NH = 28, NKV = 4;
  const int id = blockIdx.x;
  const int qt = 127 - (id >> 3);          // 16-row q tile, longest first
  const int b = (id >> 2) & 1, kvh = id & 3;
  const int tid = threadIdx.x, lane = tid & 63, wave = tid >> 6;  // wave 0..6
  const int h = kvh * 7 + wave;            // this wave's query head
  const int q0 = qt * 16;
  const int row_f = lane & 15, kg = lane >> 4, kg8 = (lane >> 4) * 8;

  __shared__ _Float16 Ks[4][64][32];   // [d_chunk][key][32 d] rows=64B
  __shared__ _Float16 Vs[2][128][32];  // [key_chunk][d][32 keys] rows=64B
  __shared__ _Float16 Ps[7][16][72];   // per-wave P^T scratch, padded stride

  // load Q fragments (A-operand layout) once
  h8 qf[4];
  {
    const _Float16* qrow = Q + ((size_t)(b * S + q0 + row_f) * NH + h) * D;
#pragma unroll
    for (int ks = 0; ks < 4; ++ks)
      qf[ks] = *(const h8*)(qrow + ks * 32 + kg8);
  }
  f4 o_acc[8] = {};
  float m_i[4] = {-1e30f, -1e30f, -1e30f, -1e30f};
  float l_i[4] = {0.f, 0.f, 0.f, 0.f};
  const float sc = 0.08838834764831845f * 1.4426950408889634f;  // scale * log2e

  const _Float16* kbase = Kh + ((size_t)(b * S) * NKV + kvh) * D;
  const _Float16* vbase = Vt + ((size_t)(b * NKV + kvh) * D) * S;

  const int kt_max = qt >> 2;  // last 64-key tile (diagonal)
  for (int kt = 0; kt <= kt_max; ++kt) {
    __syncthreads();
    if (tid < 256) {
      // stage K tile: 64 keys x 128 d, chunked by 32 d
#pragma unroll
      for (int is = 0; is < 4; ++is) {
        int off = (is * 256 + tid) * 8;
        int chunk = off >> 11;
        int key = (off >> 5) & 63;
        int dl = off & 31;
        gload_lds16(kbase + (size_t)(kt * 64 + key) * (NKV * D) + chunk * 32 + dl,
                    &Ks[0][0][0] + off);
      }
      // stage V tile: 128 d x 64 keys, chunked by 32 keys
#pragma unroll
      for (int is = 0; is < 4; ++is) {
        int off = (is * 256 + tid) * 8;
        int chunk = off >> 12;
        int d = (off >> 5) & 127;
        int kl = off & 31;
        gload_lds16(vbase + (size_t)d * S + kt * 64 + chunk * 32 + kl,
                    &Vs[0][0][0] + off);
      }
    }
    __syncthreads();

    // S = Q K^T  (16 q x 64 keys per wave)
    f4 s_acc[4] = {};
#pragma unroll
    for (int ks = 0; ks < 4; ++ks) {
#pragma unroll
      for (int nt = 0; nt < 4; ++nt) {
        h8 kf = *(const h8*)&Ks[ks][nt * 16 + row_f][kg8];
        s_acc[nt] = __builtin_amdgcn_mfma_f32_16x16x32_f16(qf[ks], kf, s_acc[nt], 0, 0, 0);
      }
    }

    // scaled scores (log2 domain) + causal mask on the diagonal tile
    float sv[4][4];
    const bool diag = (kt == kt_max);
#pragma unroll
    for (int nt = 0; nt < 4; ++nt) {
#pragma unroll
      for (int r = 0; r < 4; ++r) {
        float v = s_acc[nt][r] * sc;
        if (diag) {
          int key = kt * 64 + nt * 16 + row_f;
          int row = q0 + kg * 4 + r;
          if (key > row) v = -1e30f;
        }
        sv[nt][r] = v;
      }
    }
    // online softmax (rows live in 16-lane groups)
#pragma unroll
    for (int r = 0; r < 4; ++r) {
      float mx = fmaxf(fmaxf(sv[0][r], sv[1][r]), fmaxf(sv[2][r], sv[3][r]));
#pragma unroll
      for (int off = 8; off >= 1; off >>= 1)
        mx = fmaxf(mx, __shfl_xor(mx, off, 64));
      float mn = fmaxf(m_i[r], mx);
      float alpha = exp2f(m_i[r] - mn);
      m_i[r] = mn;
      float ssum = 0.f;
#pragma unroll
      for (int nt = 0; nt < 4; ++nt) {
        float p = exp2f(sv[nt][r] - mn);
        sv[nt][r] = p;
        ssum += p;
      }
#pragma unroll
      for (int off = 8; off >= 1; off >>= 1)
        ssum += __shfl_xor(ssum, off, 64);
      l_i[r] = l_i[r] * alpha + ssum;
#pragma unroll
      for (int dt = 0; dt < 8; ++dt) o_acc[dt][r] *= alpha;
    }
    // P (C-layout) -> Ps (A-layout source), per-wave scratch
#pragma unroll
    for (int nt = 0; nt < 4; ++nt)
#pragma unroll
      for (int r = 0; r < 4; ++r)
        Ps[wave][kg * 4 + r][nt * 16 + row_f] = (_Float16)sv[nt][r];

    // O += P V
#pragma unroll
    for (int kv = 0; kv < 2; ++kv) {
      h8 pf = *(const h8*)&Ps[wave][row_f][kv * 32 + kg8];
#pragma unroll
      for (int dt = 0; dt < 8; ++dt) {
        h8 vf = *(const h8*)&Vs[kv][dt * 16 + row_f][kg8];
        o_acc[dt] = __builtin_amdgcn_mfma_f32_16x16x32_f16(pf, vf, o_acc[dt], 0, 0, 0);
      }
    }
  }

  // epilogue: O /= l, store [token][h*128+d]
  float inv_l[4];
#pragma unroll
  for (int r = 0; r < 4; ++r) inv_l[r] = 1.0f / l_i[r];
#pragma unroll
  for (int dt = 0; dt < 8; ++dt) {
#pragma unroll
    for (int r = 0; r < 4; ++r) {
      const int tok = b * S + q0 + kg * 4 + r;
      const int d = dt * 16 + row_f;
      Oh[((size_t)tok * NH + h) * D + d] = (_Float16)(o_acc[dt][r] * inv_l[r]);
    }
  }
}

// ---------------------------------------------------------------------------
extern "C" void kernel_launch(void* const* d_in, const int* in_sizes, int n_in,
                              void* d_out, int out_size, void* d_ws, size_t ws_size,
                              hipStream_t stream) {
  const float* hidden    = (const float*)d_in[0];
  const int*   positions = (const int*)d_in[1];
  const float* Wqkv      = (const float*)d_in[2];
  const float* bqkv      = (const float*)d_in[3];
  const float* Wo        = (const float*)d_in[4];
  float* out = (float*)d_out;

  // workspace layout (bytes)
  char* ws = (char*)d_ws;
  _Float16* hs_h  = (_Float16*)(ws);              // 4096x3584 fp16 (later reused as attn out)
  _Float16* Wt    = (_Float16*)(ws + 29360128);   // max 4608x3584 fp16 (Wqkv^T then Wo^T)
  _Float16* qkv_h = (_Float16*)(ws + 62390272);   // 4096x4608 fp16
  _Float16* q_h   = (_Float16*)(ws + 100139008);  // 4096x3584 fp16
  _Float16* k_h   = (_Float16*)(ws + 129499136);  // 4096x512 fp16
  _Float16* vt_h  = (_Float16*)(ws + 133693440);  // 2x4x128x2048 fp16
  // total 137,887,744 bytes

  // 1. hidden fp32 -> fp16
  cast_f32_to_f16<<<14336, 256, 0, stream>>>((const float4*)hidden, (h4*)hs_h, 3670016);
  // 2. Wqkv^T fp16
  transpose_cast<<<dim3(4608 / 32, 3584 / 32), dim3(32, 8), 0, stream>>>(Wqkv, Wt, 3584, 4608);
  // 3. qkv = hidden @ Wqkv + b   (fp16 out)
  gemm_kernel<true, true><<<dim3(36, 32), 256, 0, stream>>>(hs_h, Wt, bqkv, qkv_h, 4096, 4608, 3584);
  // 4. rope + split + v-transpose
  rope_kernel<<<4096, 256, 0, stream>>>(qkv_h, positions, q_h, k_h, vt_h);
  // 5. Wo^T fp16 (reuse Wt; stream-ordered after GEMM1)
  transpose_cast<<<dim3(3584 / 32, 3584 / 32), dim3(32, 8), 0, stream>>>(Wo, Wt, 3584, 3584);
  // 6. flash attention -> attn fp16 (into hs_h, dead after GEMM1)
  attn_kernel<<<1024, 448, 0, stream>>>(q_h, k_h, vt_h, hs_h);
  // 7. out = attn @ Wo   (fp32 out)
  gemm_kernel<false, false><<<dim3(28, 32), 256, 0, stream>>>(hs_h, Wt, nullptr, out, 4096, 3584, 3584);
}

// Round 4
// 701.214 us; speedup vs baseline: 1.3008x; 1.0401x over previous
//
#include <hip/hip_runtime.h>
#include <hip/hip_fp16.h>

// ---------------------------------------------------------------------------
// Qwen2 attention block, MI355X (gfx950).
// B=2 S=2048 H=3584 NH=28 NKV=4 D=128  QS=3584 KVS=512 QKV=4608  M=B*S=4096
// fp16 MFMA (16x16x32) everywhere; fp32 accumulate; fp32 softmax/rope.
// R1: attention restructured for GQA K/V sharing — 7 waves/block = 7 q-heads.
// R2: attn __launch_bounds__(448,6) -> (448,2); ,6 capped VGPR at 40 -> spills.
// R3: GEMM: BK=32 -> BK=64 (two 32-chunks, half the barrier drains) and
//     __launch_bounds__(256,2) -> (256,4) (VGPR+AGPR ~120 <= 512/4=128, so
//     4 blocks/CU fit without spill). LDS 16KB -> 32KB per block.
// ---------------------------------------------------------------------------

typedef _Float16 h8 __attribute__((ext_vector_type(8)));
typedef _Float16 h4 __attribute__((ext_vector_type(4)));
typedef float f4 __attribute__((ext_vector_type(4)));

__device__ __forceinline__ void gload_lds16(const void* g, void* l) {
  __builtin_amdgcn_global_load_lds(
      (const __attribute__((address_space(1))) void*)g,
      (__attribute__((address_space(3))) void*)l, 16, 0, 0);
}

// ---------------- elementwise cast fp32 -> fp16 ----------------
__global__ __launch_bounds__(256)
void cast_f32_to_f16(const float4* __restrict__ in, h4* __restrict__ out, int n4) {
  int i = blockIdx.x * 256 + threadIdx.x;
  if (i < n4) {
    float4 v = in[i];
    h4 o;
    o.x = (_Float16)v.x; o.y = (_Float16)v.y; o.z = (_Float16)v.z; o.w = (_Float16)v.w;
    out[i] = o;
  }
}

// ---------------- transpose + cast: W[K][N] fp32 -> Wt[N][K] fp16 ----------------
__global__ __launch_bounds__(256)
void transpose_cast(const float* __restrict__ W, _Float16* __restrict__ Wt, int K, int N) {
  __shared__ float tile[32][33];
  int n0 = blockIdx.x * 32, k0 = blockIdx.y * 32;
  int tx = threadIdx.x, ty = threadIdx.y;   // block (32,8)
#pragma unroll
  for (int i = ty; i < 32; i += 8)
    tile[i][tx] = W[(size_t)(k0 + i) * N + n0 + tx];
  __syncthreads();
#pragma unroll
  for (int i = ty; i < 32; i += 8)
    Wt[(size_t)(n0 + i) * K + k0 + tx] = (_Float16)tile[tx][i];
}

// ---------------- GEMM: C[M][N] = A[M][K] * Bt[N][K]^T (+bias) ----------------
// 128x128 block tile, BK=64 (two 32-chunks), 256 threads (2x2 waves of 64x64),
// 16x16x32 fp16 MFMA. K must be divisible by 64.
template <bool OUT_H, bool BIAS>
__global__ __launch_bounds__(256, 4)
void gemm_kernel(const _Float16* __restrict__ A, const _Float16* __restrict__ Bt,
                 const float* __restrict__ bias, void* __restrict__ Cout,
                 int M, int N, int K) {
  __shared__ _Float16 As[2 * 128 * 32];   // [chunk][row128][32]
  __shared__ _Float16 Bs[2 * 128 * 32];
  const int tid = threadIdx.x;
  const int m0 = blockIdx.y * 128, n0 = blockIdx.x * 128;
  const int lane = tid & 63, wave = tid >> 6;
  const int wm = (wave >> 1) * 64, wn = (wave & 1) * 64;
  const int r_ld = tid >> 2;          // staging row (0..63)
  const int c_ld = (tid & 3) * 8;     // staging k-offset within 32-chunk
  const int row_f = lane & 15, kg8 = (lane >> 4) * 8;

  f4 acc[4][4] = {};
  const _Float16* Ag = A + (size_t)m0 * K + c_ld;
  const _Float16* Bg = Bt + (size_t)n0 * K + c_ld;

  for (int kk = 0; kk < K; kk += 64) {
    __syncthreads();
    // stage A/B: chunk c covers cols [kk+c*32, kk+c*32+32), instr i rows [i*64,..)
#pragma unroll
    for (int c = 0; c < 2; ++c) {
#pragma unroll
      for (int i = 0; i < 2; ++i) {
        gload_lds16(Ag + (size_t)(r_ld + i * 64) * K + kk + c * 32,
                    As + c * 4096 + i * 2048 + tid * 8);
        gload_lds16(Bg + (size_t)(r_ld + i * 64) * K + kk + c * 32,
                    Bs + c * 4096 + i * 2048 + tid * 8);
      }
    }
    __syncthreads();
#pragma unroll
    for (int hf = 0; hf < 2; ++hf) {
      h8 a_frag[4], b_frag[4];
#pragma unroll
      for (int t = 0; t < 4; ++t)
        a_frag[t] = *(const h8*)&As[hf * 4096 + (wm + t * 16 + row_f) * 32 + kg8];
#pragma unroll
      for (int t = 0; t < 4; ++t)
        b_frag[t] = *(const h8*)&Bs[hf * 4096 + (wn + t * 16 + row_f) * 32 + kg8];
#pragma unroll
      for (int i = 0; i < 4; ++i)
#pragma unroll
        for (int j = 0; j < 4; ++j)
          acc[i][j] = __builtin_amdgcn_mfma_f32_16x16x32_f16(a_frag[i], b_frag[j], acc[i][j], 0, 0, 0);
    }
  }

  // epilogue: C/D layout col = lane&15, row = (lane>>4)*4 + r
  const int col_f = lane & 15, rgrp = (lane >> 4) * 4;
#pragma unroll
  for (int i = 0; i < 4; ++i) {
#pragma unroll
    for (int j = 0; j < 4; ++j) {
      const int col = n0 + wn + j * 16 + col_f;
      float bv = 0.0f;
      if (BIAS) bv = bias[col];
#pragma unroll
      for (int r = 0; r < 4; ++r) {
        const int row = m0 + wm + i * 16 + rgrp + r;
        const float v = acc[i][j][r] + bv;
        if (OUT_H) ((_Float16*)Cout)[(size_t)row * N + col] = (_Float16)v;
        else       ((float*)Cout)[(size_t)row * N + col] = v;
      }
    }
  }
}

// ---------------- RoPE + split + V transpose ----------------
__global__ __launch_bounds__(256)
void rope_kernel(const _Float16* __restrict__ qkv, const int* __restrict__ pos,
                 _Float16* __restrict__ q, _Float16* __restrict__ k,
                 _Float16* __restrict__ vt) {
  constexpr int S = 2048, NH = 28, NKV = 4, QKVW = 4608, QW = 3584, KVW = 512;
  const int token = blockIdx.x;
  const int b = token >> 11, s = token & 2047;
  const int p = pos[token];
  __shared__ float cs[64], sn[64];
  const int tid = threadIdx.x;
  if (tid < 64) {
    const float L = 0.31143075892695140f;  // log2(1e6)/64
    float inv = exp2f(-(float)tid * L);
    float ang = (float)p * inv;
    cs[tid] = cosf(ang);
    sn[tid] = sinf(ang);
  }
  __syncthreads();
  const _Float16* src = qkv + (size_t)token * QKVW;
  for (int i = tid; i < NH * 64; i += 256) {
    int hh = i >> 6, d = i & 63;
    float x1 = (float)src[hh * 128 + d];
    float x2 = (float)src[hh * 128 + d + 64];
    float c = cs[d], sv = sn[d];
    _Float16* dst = q + (size_t)token * QW + hh * 128 + d;
    dst[0]  = (_Float16)(x1 * c - x2 * sv);
    dst[64] = (_Float16)(x2 * c + x1 * sv);
  }
  for (int i = tid; i < NKV * 64; i += 256) {
    int hh = i >> 6, d = i & 63;
    float x1 = (float)src[QW + hh * 128 + d];
    float x2 = (float)src[QW + hh * 128 + d + 64];
    float c = cs[d], sv = sn[d];
    _Float16* dst = k + (size_t)token * KVW + hh * 128 + d;
    dst[0]  = (_Float16)(x1 * c - x2 * sv);
    dst[64] = (_Float16)(x2 * c + x1 * sv);
  }
  for (int i = tid; i < NKV * 128; i += 256) {
    int hh = i >> 7, d = i & 127;
    vt[(((size_t)b * NKV + hh) * 128 + d) * S + s] = src[QW + KVW + hh * 128 + d];
  }
}

// ---------------- flash attention (causal, GQA, KV shared across 7 heads) ----
// grid 1024 blocks x 448 threads. Block = (16 q-rows) x (7 heads of one kvh).
// wave w handles head kvh*7+w. K/V staged once per 64-key tile, shared.
// LPT: qt mapped descending so longest blocks dispatch first.
// launch_bounds (448,2): VGPR cap 256 — DO NOT tighten; (448,6) caused spills.
__global__ __launch_bounds__(448, 2)
void attn_kernel(const _Float16* __restrict__ Q,   // [B*S][NH*128] rope'd
                 const _Float16* __restrict__ Kh,  // [B*S][NKV*128] rope'd
                 const _Float16* __restrict__ Vt,  // [B][NKV][128][S]
                 _Float16* __restrict__ Oh) {      // [B*S][NH*128]
  constexpr int S = 2048, D = 128, NH = 28, NKV = 4;
  const int id = blockIdx.x;
  const int qt = 127 - (id >> 3);          // 16-row q tile, longest first
  const int b = (id >> 2) & 1, kvh = id & 3;
  const int tid = threadIdx.x, lane = tid & 63, wave = tid >> 6;  // wave 0..6
  const int h = kvh * 7 + wave;            // this wave's query head
  const int q0 = qt * 16;
  const int row_f = lane & 15, kg = lane >> 4, kg8 = (lane >> 4) * 8;

  __shared__ _Float16 Ks[4][64][32];   // [d_chunk][key][32 d] rows=64B
  __shared__ _Float16 Vs[2][128][32];  // [key_chunk][d][32 keys] rows=64B
  __shared__ _Float16 Ps[7][16][72];   // per-wave P^T scratch, padded stride

  // load Q fragments (A-operand layout) once
  h8 qf[4];
  {
    const _Float16* qrow = Q + ((size_t)(b * S + q0 + row_f) * NH + h) * D;
#pragma unroll
    for (int ks = 0; ks < 4; ++ks)
      qf[ks] = *(const h8*)(qrow + ks * 32 + kg8);
  }
  f4 o_acc[8] = {};
  float m_i[4] = {-1e30f, -1e30f, -1e30f, -1e30f};
  float l_i[4] = {0.f, 0.f, 0.f, 0.f};
  const float sc = 0.08838834764831845f * 1.4426950408889634f;  // scale * log2e

  const _Float16* kbase = Kh + ((size_t)(b * S) * NKV + kvh) * D;
  const _Float16* vbase = Vt + ((size_t)(b * NKV + kvh) * D) * S;

  const int kt_max = qt >> 2;  // last 64-key tile (diagonal)
  for (int kt = 0; kt <= kt_max; ++kt) {
    __syncthreads();
    if (tid < 256) {
      // stage K tile: 64 keys x 128 d, chunked by 32 d
#pragma unroll
      for (int is = 0; is < 4; ++is) {
        int off = (is * 256 + tid) * 8;
        int chunk = off >> 11;
        int key = (off >> 5) & 63;
        int dl = off & 31;
        gload_lds16(kbase + (size_t)(kt * 64 + key) * (NKV * D) + chunk * 32 + dl,
                    &Ks[0][0][0] + off);
      }
      // stage V tile: 128 d x 64 keys, chunked by 32 keys
#pragma unroll
      for (int is = 0; is < 4; ++is) {
        int off = (is * 256 + tid) * 8;
        int chunk = off >> 12;
        int d = (off >> 5) & 127;
        int kl = off & 31;
        gload_lds16(vbase + (size_t)d * S + kt * 64 + chunk * 32 + kl,
                    &Vs[0][0][0] + off);
      }
    }
    __syncthreads();

    // S = Q K^T  (16 q x 64 keys per wave)
    f4 s_acc[4] = {};
#pragma unroll
    for (int ks = 0; ks < 4; ++ks) {
#pragma unroll
      for (int nt = 0; nt < 4; ++nt) {
        h8 kf = *(const h8*)&Ks[ks][nt * 16 + row_f][kg8];
        s_acc[nt] = __builtin_amdgcn_mfma_f32_16x16x32_f16(qf[ks], kf, s_acc[nt], 0, 0, 0);
      }
    }

    // scaled scores (log2 domain) + causal mask on the diagonal tile
    float sv[4][4];
    const bool diag = (kt == kt_max);
#pragma unroll
    for (int nt = 0; nt < 4; ++nt) {
#pragma unroll
      for (int r = 0; r < 4; ++r) {
        float v = s_acc[nt][r] * sc;
        if (diag) {
          int key = kt * 64 + nt * 16 + row_f;
          int row = q0 + kg * 4 + r;
          if (key > row) v = -1e30f;
        }
        sv[nt][r] = v;
      }
    }
    // online softmax (rows live in 16-lane groups)
#pragma unroll
    for (int r = 0; r < 4; ++r) {
      float mx = fmaxf(fmaxf(sv[0][r], sv[1][r]), fmaxf(sv[2][r], sv[3][r]));
#pragma unroll
      for (int off = 8; off >= 1; off >>= 1)
        mx = fmaxf(mx, __shfl_xor(mx, off, 64));
      float mn = fmaxf(m_i[r], mx);
      float alpha = exp2f(m_i[r] - mn);
      m_i[r] = mn;
      float ssum = 0.f;
#pragma unroll
      for (int nt = 0; nt < 4; ++nt) {
        float p = exp2f(sv[nt][r] - mn);
        sv[nt][r] = p;
        ssum += p;
      }
#pragma unroll
      for (int off = 8; off >= 1; off >>= 1)
        ssum += __shfl_xor(ssum, off, 64);
      l_i[r] = l_i[r] * alpha + ssum;
#pragma unroll
      for (int dt = 0; dt < 8; ++dt) o_acc[dt][r] *= alpha;
    }
    // P (C-layout) -> Ps (A-layout source), per-wave scratch
#pragma unroll
    for (int nt = 0; nt < 4; ++nt)
#pragma unroll
      for (int r = 0; r < 4; ++r)
        Ps[wave][kg * 4 + r][nt * 16 + row_f] = (_Float16)sv[nt][r];

    // O += P V
#pragma unroll
    for (int kv = 0; kv < 2; ++kv) {
      h8 pf = *(const h8*)&Ps[wave][row_f][kv * 32 + kg8];
#pragma unroll
      for (int dt = 0; dt < 8; ++dt) {
        h8 vf = *(const h8*)&Vs[kv][dt * 16 + row_f][kg8];
        o_acc[dt] = __builtin_amdgcn_mfma_f32_16x16x32_f16(pf, vf, o_acc[dt], 0, 0, 0);
      }
    }
  }

  // epilogue: O /= l, store [token][h*128+d]
  float inv_l[4];
#pragma unroll
  for (int r = 0; r < 4; ++r) inv_l[r] = 1.0f / l_i[r];
#pragma unroll
  for (int dt = 0; dt < 8; ++dt) {
#pragma unroll
    for (int r = 0; r < 4; ++r) {
      const int tok = b * S + q0 + kg * 4 + r;
      const int d = dt * 16 + row_f;
      Oh[((size_t)tok * NH + h) * D + d] = (_Float16)(o_acc[dt][r] * inv_l[r]);
    }
  }
}

// ---------------------------------------------------------------------------
extern "C" void kernel_launch(void* const* d_in, const int* in_sizes, int n_in,
                              void* d_out, int out_size, void* d_ws, size_t ws_size,
                              hipStream_t stream) {
  const float* hidden    = (const float*)d_in[0];
  const int*   positions = (const int*)d_in[1];
  const float* Wqkv      = (const float*)d_in[2];
  const float* bqkv      = (const float*)d_in[3];
  const float* Wo        = (const float*)d_in[4];
  float* out = (float*)d_out;

  // workspace layout (bytes)
  char* ws = (char*)d_ws;
  _Float16* hs_h  = (_Float16*)(ws);              // 4096x3584 fp16 (later reused as attn out)
  _Float16* Wt    = (_Float16*)(ws + 29360128);   // max 4608x3584 fp16 (Wqkv^T then Wo^T)
  _Float16* qkv_h = (_Float16*)(ws + 62390272);   // 4096x4608 fp16
  _Float16* q_h   = (_Float16*)(ws + 100139008);  // 4096x3584 fp16
  _Float16* k_h   = (_Float16*)(ws + 129499136);  // 4096x512 fp16
  _Float16* vt_h  = (_Float16*)(ws + 133693440);  // 2x4x128x2048 fp16
  // total 137,887,744 bytes

  // 1. hidden fp32 -> fp16
  cast_f32_to_f16<<<14336, 256, 0, stream>>>((const float4*)hidden, (h4*)hs_h, 3670016);
  // 2. Wqkv^T fp16
  transpose_cast<<<dim3(4608 / 32, 3584 / 32), dim3(32, 8), 0, stream>>>(Wqkv, Wt, 3584, 4608);
  // 3. qkv = hidden @ Wqkv + b   (fp16 out)
  gemm_kernel<true, true><<<dim3(36, 32), 256, 0, stream>>>(hs_h, Wt, bqkv, qkv_h, 4096, 4608, 3584);
  // 4. rope + split + v-transpose
  rope_kernel<<<4096, 256, 0, stream>>>(qkv_h, positions, q_h, k_h, vt_h);
  // 5. Wo^T fp16 (reuse Wt; stream-ordered after GEMM1)
  transpose_cast<<<dim3(3584 / 32, 3584 / 32), dim3(32, 8), 0, stream>>>(Wo, Wt, 3584, 3584);
  // 6. flash attention -> attn fp16 (into hs_h, dead after GEMM1)
  attn_kernel<<<1024, 448, 0, stream>>>(q_h, k_h, vt_h, hs_h);
  // 7. out = attn @ Wo   (fp32 out)
  gemm_kernel<false, false><<<dim3(28, 32), 256, 0, stream>>>(hs_h, Wt, nullptr, out, 4096, 3584, 3584);
}

// Round 5
// 679.535 us; speedup vs baseline: 1.3423x; 1.0319x over previous
//
#include <hip/hip_runtime.h>
#include <hip/hip_fp16.h>

// ---------------------------------------------------------------------------
// Qwen2 attention block, MI355X (gfx950).
// B=2 S=2048 H=3584 NH=28 NKV=4 D=128  QS=3584 KVS=512 QKV=4608  M=B*S=4096
// fp16 MFMA (16x16x32) everywhere; fp32 accumulate; fp32 softmax/rope.
// R1: attention restructured for GQA K/V sharing — 7 waves/block = 7 q-heads.
// R2: attn __launch_bounds__(448,6) -> (448,2); ,6 capped VGPR at 40 -> spills.
// R3: GEMM BK=32 -> BK=64, (256,2) -> (256,4).
// R4: GEMM1 grid 36x32=1152 vs 1024 slots = 1.125 rounds -> measured 2-round
//     tail (occupancy 29% == (4+0.5)/2/16 exactly). New 128x192-tile kernel:
//     grid 24x32=768 = exactly 3 blocks/CU (LDS 40KB*3=120KB, ~155 regs <=
//     170 cap at (256,3)) -> no tail. GEMM2 (896 blocks < 1024) unchanged.
// ---------------------------------------------------------------------------

typedef _Float16 h8 __attribute__((ext_vector_type(8)));
typedef _Float16 h4 __attribute__((ext_vector_type(4)));
typedef float f4 __attribute__((ext_vector_type(4)));

__device__ __forceinline__ void gload_lds16(const void* g, void* l) {
  __builtin_amdgcn_global_load_lds(
      (const __attribute__((address_space(1))) void*)g,
      (__attribute__((address_space(3))) void*)l, 16, 0, 0);
}

// ---------------- elementwise cast fp32 -> fp16 ----------------
__global__ __launch_bounds__(256)
void cast_f32_to_f16(const float4* __restrict__ in, h4* __restrict__ out, int n4) {
  int i = blockIdx.x * 256 + threadIdx.x;
  if (i < n4) {
    float4 v = in[i];
    h4 o;
    o.x = (_Float16)v.x; o.y = (_Float16)v.y; o.z = (_Float16)v.z; o.w = (_Float16)v.w;
    out[i] = o;
  }
}

// ---------------- transpose + cast: W[K][N] fp32 -> Wt[N][K] fp16 ----------------
__global__ __launch_bounds__(256)
void transpose_cast(const float* __restrict__ W, _Float16* __restrict__ Wt, int K, int N) {
  __shared__ float tile[32][33];
  int n0 = blockIdx.x * 32, k0 = blockIdx.y * 32;
  int tx = threadIdx.x, ty = threadIdx.y;   // block (32,8)
#pragma unroll
  for (int i = ty; i < 32; i += 8)
    tile[i][tx] = W[(size_t)(k0 + i) * N + n0 + tx];
  __syncthreads();
#pragma unroll
  for (int i = ty; i < 32; i += 8)
    Wt[(size_t)(n0 + i) * K + k0 + tx] = (_Float16)tile[tx][i];
}

// ---------------- GEMM1: 128x192 tile, grid-exact (24x32=768=3/CU) ----------
// C[M][N] = A[M][K] * Bt[N][K]^T + bias, fp16 out. BK=64 (two 32-chunks).
// 256 threads = 2x2 waves; wave tile 64x96 (4x6 MFMA tiles, 96 AGPR acc).
__global__ __launch_bounds__(256, 3)
void gemm_wide(const _Float16* __restrict__ A, const _Float16* __restrict__ Bt,
               const float* __restrict__ bias, _Float16* __restrict__ Cout,
               int M, int N, int K) {
  __shared__ _Float16 As[2 * 128 * 32];   // [chunk][row128][32] = 16 KB
  __shared__ _Float16 Bs[2 * 192 * 32];   // [chunk][row192][32] = 24 KB
  const int tid = threadIdx.x;
  const int m0 = blockIdx.y * 128, n0 = blockIdx.x * 192;
  const int lane = tid & 63, wave = tid >> 6;
  const int wm = (wave >> 1) * 64, wn = (wave & 1) * 96;
  const int r_ld = tid >> 2;          // staging row (0..63)
  const int c_ld = (tid & 3) * 8;     // staging k-offset within 32-chunk
  const int row_f = lane & 15, kg8 = (lane >> 4) * 8;

  f4 acc[4][6] = {};
  const _Float16* Ag = A + (size_t)m0 * K + c_ld;
  const _Float16* Bg = Bt + (size_t)n0 * K + c_ld;

  for (int kk = 0; kk < K; kk += 64) {
    __syncthreads();
#pragma unroll
    for (int c = 0; c < 2; ++c) {
#pragma unroll
      for (int i = 0; i < 2; ++i)
        gload_lds16(Ag + (size_t)(r_ld + i * 64) * K + kk + c * 32,
                    As + c * 4096 + i * 2048 + tid * 8);
#pragma unroll
      for (int i = 0; i < 3; ++i)
        gload_lds16(Bg + (size_t)(r_ld + i * 64) * K + kk + c * 32,
                    Bs + c * 6144 + i * 2048 + tid * 8);
    }
    __syncthreads();
#pragma unroll
    for (int hf = 0; hf < 2; ++hf) {
      h8 a_frag[4], b_frag[6];
#pragma unroll
      for (int t = 0; t < 4; ++t)
        a_frag[t] = *(const h8*)&As[hf * 4096 + (wm + t * 16 + row_f) * 32 + kg8];
#pragma unroll
      for (int t = 0; t < 6; ++t)
        b_frag[t] = *(const h8*)&Bs[hf * 6144 + (wn + t * 16 + row_f) * 32 + kg8];
#pragma unroll
      for (int i = 0; i < 4; ++i)
#pragma unroll
        for (int j = 0; j < 6; ++j)
          acc[i][j] = __builtin_amdgcn_mfma_f32_16x16x32_f16(a_frag[i], b_frag[j], acc[i][j], 0, 0, 0);
    }
  }

  // epilogue: C/D layout col = lane&15, row = (lane>>4)*4 + r
  const int col_f = lane & 15, rgrp = (lane >> 4) * 4;
#pragma unroll
  for (int i = 0; i < 4; ++i) {
#pragma unroll
    for (int j = 0; j < 6; ++j) {
      const int col = n0 + wn + j * 16 + col_f;
      const float bv = bias[col];
#pragma unroll
      for (int r = 0; r < 4; ++r) {
        const int row = m0 + wm + i * 16 + rgrp + r;
        Cout[(size_t)row * N + col] = (_Float16)(acc[i][j][r] + bv);
      }
    }
  }
}

// ---------------- GEMM: C[M][N] = A[M][K] * Bt[N][K]^T (+bias) ----------------
// 128x128 block tile, BK=64 (two 32-chunks), 256 threads (2x2 waves of 64x64),
// 16x16x32 fp16 MFMA. K must be divisible by 64. Used for GEMM2 (896 blocks).
template <bool OUT_H, bool BIAS>
__global__ __launch_bounds__(256, 4)
void gemm_kernel(const _Float16* __restrict__ A, const _Float16* __restrict__ Bt,
                 const float* __restrict__ bias, void* __restrict__ Cout,
                 int M, int N, int K) {
  __shared__ _Float16 As[2 * 128 * 32];   // [chunk][row128][32]
  __shared__ _Float16 Bs[2 * 128 * 32];
  const int tid = threadIdx.x;
  const int m0 = blockIdx.y * 128, n0 = blockIdx.x * 128;
  const int lane = tid & 63, wave = tid >> 6;
  const int wm = (wave >> 1) * 64, wn = (wave & 1) * 64;
  const int r_ld = tid >> 2;          // staging row (0..63)
  const int c_ld = (tid & 3) * 8;     // staging k-offset within 32-chunk
  const int row_f = lane & 15, kg8 = (lane >> 4) * 8;

  f4 acc[4][4] = {};
  const _Float16* Ag = A + (size_t)m0 * K + c_ld;
  const _Float16* Bg = Bt + (size_t)n0 * K + c_ld;

  for (int kk = 0; kk < K; kk += 64) {
    __syncthreads();
#pragma unroll
    for (int c = 0; c < 2; ++c) {
#pragma unroll
      for (int i = 0; i < 2; ++i) {
        gload_lds16(Ag + (size_t)(r_ld + i * 64) * K + kk + c * 32,
                    As + c * 4096 + i * 2048 + tid * 8);
        gload_lds16(Bg + (size_t)(r_ld + i * 64) * K + kk + c * 32,
                    Bs + c * 4096 + i * 2048 + tid * 8);
      }
    }
    __syncthreads();
#pragma unroll
    for (int hf = 0; hf < 2; ++hf) {
      h8 a_frag[4], b_frag[4];
#pragma unroll
      for (int t = 0; t < 4; ++t)
        a_frag[t] = *(const h8*)&As[hf * 4096 + (wm + t * 16 + row_f) * 32 + kg8];
#pragma unroll
      for (int t = 0; t < 4; ++t)
        b_frag[t] = *(const h8*)&Bs[hf * 4096 + (wn + t * 16 + row_f) * 32 + kg8];
#pragma unroll
      for (int i = 0; i < 4; ++i)
#pragma unroll
        for (int j = 0; j < 4; ++j)
          acc[i][j] = __builtin_amdgcn_mfma_f32_16x16x32_f16(a_frag[i], b_frag[j], acc[i][j], 0, 0, 0);
    }
  }

  // epilogue: C/D layout col = lane&15, row = (lane>>4)*4 + r
  const int col_f = lane & 15, rgrp = (lane >> 4) * 4;
#pragma unroll
  for (int i = 0; i < 4; ++i) {
#pragma unroll
    for (int j = 0; j < 4; ++j) {
      const int col = n0 + wn + j * 16 + col_f;
      float bv = 0.0f;
      if (BIAS) bv = bias[col];
#pragma unroll
      for (int r = 0; r < 4; ++r) {
        const int row = m0 + wm + i * 16 + rgrp + r;
        const float v = acc[i][j][r] + bv;
        if (OUT_H) ((_Float16*)Cout)[(size_t)row * N + col] = (_Float16)v;
        else       ((float*)Cout)[(size_t)row * N + col] = v;
      }
    }
  }
}

// ---------------- RoPE + split + V transpose ----------------
__global__ __launch_bounds__(256)
void rope_kernel(const _Float16* __restrict__ qkv, const int* __restrict__ pos,
                 _Float16* __restrict__ q, _Float16* __restrict__ k,
                 _Float16* __restrict__ vt) {
  constexpr int S = 2048, NH = 28, NKV = 4, QKVW = 4608, QW = 3584, KVW = 512;
  const int token = blockIdx.x;
  const int b = token >> 11, s = token & 2047;
  const int p = pos[token];
  __shared__ float cs[64], sn[64];
  const int tid = threadIdx.x;
  if (tid < 64) {
    const float L = 0.31143075892695140f;  // log2(1e6)/64
    float inv = exp2f(-(float)tid * L);
    float ang = (float)p * inv;
    cs[tid] = cosf(ang);
    sn[tid] = sinf(ang);
  }
  __syncthreads();
  const _Float16* src = qkv + (size_t)token * QKVW;
  for (int i = tid; i < NH * 64; i += 256) {
    int hh = i >> 6, d = i & 63;
    float x1 = (float)src[hh * 128 + d];
    float x2 = (float)src[hh * 128 + d + 64];
    float c = cs[d], sv = sn[d];
    _Float16* dst = q + (size_t)token * QW + hh * 128 + d;
    dst[0]  = (_Float16)(x1 * c - x2 * sv);
    dst[64] = (_Float16)(x2 * c + x1 * sv);
  }
  for (int i = tid; i < NKV * 64; i += 256) {
    int hh = i >> 6, d = i & 63;
    float x1 = (float)src[QW + hh * 128 + d];
    float x2 = (float)src[QW + hh * 128 + d + 64];
    float c = cs[d], sv = sn[d];
    _Float16* dst = k + (size_t)token * KVW + hh * 128 + d;
    dst[0]  = (_Float16)(x1 * c - x2 * sv);
    dst[64] = (_Float16)(x2 * c + x1 * sv);
  }
  for (int i = tid; i < NKV * 128; i += 256) {
    int hh = i >> 7, d = i & 127;
    vt[(((size_t)b * NKV + hh) * 128 + d) * S + s] = src[QW + KVW + hh * 128 + d];
  }
}

// ---------------- flash attention (causal, GQA, KV shared across 7 heads) ----
// grid 1024 blocks x 448 threads. Block = (16 q-rows) x (7 heads of one kvh).
// wave w handles head kvh*7+w. K/V staged once per 64-key tile, shared.
// LPT: qt mapped descending so longest blocks dispatch first.
// launch_bounds (448,2): VGPR cap 256 — DO NOT tighten; (448,6) caused spills.
__global__ __launch_bounds__(448, 2)
void attn_kernel(const _Float16* __restrict__ Q,   // [B*S][NH*128] rope'd
                 const _Float16* __restrict__ Kh,  // [B*S][NKV*128] rope'd
                 const _Float16* __restrict__ Vt,  // [B][NKV][128][S]
                 _Float16* __restrict__ Oh) {      // [B*S][NH*128]
  constexpr int S = 2048, D = 128, NH = 28, NKV = 4;
  const int id = blockIdx.x;
  const int qt = 127 - (id >> 3);          // 16-row q tile, longest first
  const int b = (id >> 2) & 1, kvh = id & 3;
  const int tid = threadIdx.x, lane = tid & 63, wave = tid >> 6;  // wave 0..6
  const int h = kvh * 7 + wave;            // this wave's query head
  const int q0 = qt * 16;
  const int row_f = lane & 15, kg = lane >> 4, kg8 = (lane >> 4) * 8;

  __shared__ _Float16 Ks[4][64][32];   // [d_chunk][key][32 d] rows=64B
  __shared__ _Float16 Vs[2][128][32];  // [key_chunk][d][32 keys] rows=64B
  __shared__ _Float16 Ps[7][16][72];   // per-wave P^T scratch, padded stride

  // load Q fragments (A-operand layout) once
  h8 qf[4];
  {
    const _Float16* qrow = Q + ((size_t)(b * S + q0 + row_f) * NH + h) * D;
#pragma unroll
    for (int ks = 0; ks < 4; ++ks)
      qf[ks] = *(const h8*)(qrow + ks * 32 + kg8);
  }
  f4 o_acc[8] = {};
  float m_i[4] = {-1e30f, -1e30f, -1e30f, -1e30f};
  float l_i[4] = {0.f, 0.f, 0.f, 0.f};
  const float sc = 0.08838834764831845f * 1.4426950408889634f;  // scale * log2e

  const _Float16* kbase = Kh + ((size_t)(b * S) * NKV + kvh) * D;
  const _Float16* vbase = Vt + ((size_t)(b * NKV + kvh) * D) * S;

  const int kt_max = qt >> 2;  // last 64-key tile (diagonal)
  for (int kt = 0; kt <= kt_max; ++kt) {
    __syncthreads();
    if (tid < 256) {
      // stage K tile: 64 keys x 128 d, chunked by 32 d
#pragma unroll
      for (int is = 0; is < 4; ++is) {
        int off = (is * 256 + tid) * 8;
        int chunk = off >> 11;
        int key = (off >> 5) & 63;
        int dl = off & 31;
        gload_lds16(kbase + (size_t)(kt * 64 + key) * (NKV * D) + chunk * 32 + dl,
                    &Ks[0][0][0] + off);
      }
      // stage V tile: 128 d x 64 keys, chunked by 32 keys
#pragma unroll
      for (int is = 0; is < 4; ++is) {
        int off = (is * 256 + tid) * 8;
        int chunk = off >> 12;
        int d = (off >> 5) & 127;
        int kl = off & 31;
        gload_lds16(vbase + (size_t)d * S + kt * 64 + chunk * 32 + kl,
                    &Vs[0][0][0] + off);
      }
    }
    __syncthreads();

    // S = Q K^T  (16 q x 64 keys per wave)
    f4 s_acc[4] = {};
#pragma unroll
    for (int ks = 0; ks < 4; ++ks) {
#pragma unroll
      for (int nt = 0; nt < 4; ++nt) {
        h8 kf = *(const h8*)&Ks[ks][nt * 16 + row_f][kg8];
        s_acc[nt] = __builtin_amdgcn_mfma_f32_16x16x32_f16(qf[ks], kf, s_acc[nt], 0, 0, 0);
      }
    }

    // scaled scores (log2 domain) + causal mask on the diagonal tile
    float sv[4][4];
    const bool diag = (kt == kt_max);
#pragma unroll
    for (int nt = 0; nt < 4; ++nt) {
#pragma unroll
      for (int r = 0; r < 4; ++r) {
        float v = s_acc[nt][r] * sc;
        if (diag) {
          int key = kt * 64 + nt * 16 + row_f;
          int row = q0 + kg * 4 + r;
          if (key > row) v = -1e30f;
        }
        sv[nt][r] = v;
      }
    }
    // online softmax (rows live in 16-lane groups)
#pragma unroll
    for (int r = 0; r < 4; ++r) {
      float mx = fmaxf(fmaxf(sv[0][r], sv[1][r]), fmaxf(sv[2][r], sv[3][r]));
#pragma unroll
      for (int off = 8; off >= 1; off >>= 1)
        mx = fmaxf(mx, __shfl_xor(mx, off, 64));
      float mn = fmaxf(m_i[r], mx);
      float alpha = exp2f(m_i[r] - mn);
      m_i[r] = mn;
      float ssum = 0.f;
#pragma unroll
      for (int nt = 0; nt < 4; ++nt) {
        float p = exp2f(sv[nt][r] - mn);
        sv[nt][r] = p;
        ssum += p;
      }
#pragma unroll
      for (int off = 8; off >= 1; off >>= 1)
        ssum += __shfl_xor(ssum, off, 64);
      l_i[r] = l_i[r] * alpha + ssum;
#pragma unroll
      for (int dt = 0; dt < 8; ++dt) o_acc[dt][r] *= alpha;
    }
    // P (C-layout) -> Ps (A-layout source), per-wave scratch
#pragma unroll
    for (int nt = 0; nt < 4; ++nt)
#pragma unroll
      for (int r = 0; r < 4; ++r)
        Ps[wave][kg * 4 + r][nt * 16 + row_f] = (_Float16)sv[nt][r];

    // O += P V
#pragma unroll
    for (int kv = 0; kv < 2; ++kv) {
      h8 pf = *(const h8*)&Ps[wave][row_f][kv * 32 + kg8];
#pragma unroll
      for (int dt = 0; dt < 8; ++dt) {
        h8 vf = *(const h8*)&Vs[kv][dt * 16 + row_f][kg8];
        o_acc[dt] = __builtin_amdgcn_mfma_f32_16x16x32_f16(pf, vf, o_acc[dt], 0, 0, 0);
      }
    }
  }

  // epilogue: O /= l, store [token][h*128+d]
  float inv_l[4];
#pragma unroll
  for (int r = 0; r < 4; ++r) inv_l[r] = 1.0f / l_i[r];
#pragma unroll
  for (int dt = 0; dt < 8; ++dt) {
#pragma unroll
    for (int r = 0; r < 4; ++r) {
      const int tok = b * S + q0 + kg * 4 + r;
      const int d = dt * 16 + row_f;
      Oh[((size_t)tok * NH + h) * D + d] = (_Float16)(o_acc[dt][r] * inv_l[r]);
    }
  }
}

// ---------------------------------------------------------------------------
extern "C" void kernel_launch(void* const* d_in, const int* in_sizes, int n_in,
                              void* d_out, int out_size, void* d_ws, size_t ws_size,
                              hipStream_t stream) {
  const float* hidden    = (const float*)d_in[0];
  const int*   positions = (const int*)d_in[1];
  const float* Wqkv      = (const float*)d_in[2];
  const float* bqkv      = (const float*)d_in[3];
  const float* Wo        = (const float*)d_in[4];
  float* out = (float*)d_out;

  // workspace layout (bytes)
  char* ws = (char*)d_ws;
  _Float16* hs_h  = (_Float16*)(ws);              // 4096x3584 fp16 (later reused as attn out)
  _Float16* Wt    = (_Float16*)(ws + 29360128);   // max 4608x3584 fp16 (Wqkv^T then Wo^T)
  _Float16* qkv_h = (_Float16*)(ws + 62390272);   // 4096x4608 fp16
  _Float16* q_h   = (_Float16*)(ws + 100139008);  // 4096x3584 fp16
  _Float16* k_h   = (_Float16*)(ws + 129499136);  // 4096x512 fp16
  _Float16* vt_h  = (_Float16*)(ws + 133693440);  // 2x4x128x2048 fp16
  // total 137,887,744 bytes

  // 1. hidden fp32 -> fp16
  cast_f32_to_f16<<<14336, 256, 0, stream>>>((const float4*)hidden, (h4*)hs_h, 3670016);
  // 2. Wqkv^T fp16
  transpose_cast<<<dim3(4608 / 32, 3584 / 32), dim3(32, 8), 0, stream>>>(Wqkv, Wt, 3584, 4608);
  // 3. qkv = hidden @ Wqkv + b   (fp16 out) — 128x192 tiles, grid-exact 768
  gemm_wide<<<dim3(24, 32), 256, 0, stream>>>(hs_h, Wt, bqkv, qkv_h, 4096, 4608, 3584);
  // 4. rope + split + v-transpose
  rope_kernel<<<4096, 256, 0, stream>>>(qkv_h, positions, q_h, k_h, vt_h);
  // 5. Wo^T fp16 (reuse Wt; stream-ordered after GEMM1)
  transpose_cast<<<dim3(3584 / 32, 3584 / 32), dim3(32, 8), 0, stream>>>(Wo, Wt, 3584, 3584);
  // 6. flash attention -> attn fp16 (into hs_h, dead after GEMM1)
  attn_kernel<<<1024, 448, 0, stream>>>(q_h, k_h, vt_h, hs_h);
  // 7. out = attn @ Wo   (fp32 out)
  gemm_kernel<false, false><<<dim3(28, 32), 256, 0, stream>>>(hs_h, Wt, nullptr, out, 4096, 3584, 3584);
}